// Round 3
// baseline (494.831 us; speedup 1.0000x reference)
//
#include <hip/hip_runtime.h>
#include <hip/hip_bf16.h>
#include <math.h>

#define NEG_MASK -999999.0f

constexpr int BB = 64, PP = 512, HH = 512, DD = 512;

typedef _Float16 h8    __attribute__((ext_vector_type(8)));   // MFMA A/B operand (4 VGPRs)
typedef float    f32x4 __attribute__((ext_vector_type(4)));
typedef float    f32x2 __attribute__((ext_vector_type(2)));

#define MFMA16(a, b, c) __builtin_amdgcn_mfma_f32_16x16x32_f16(a, b, c, 0, 0, 0)

// Bijective XOR swizzle for [128 rows][64 bytes] LDS tiles. 16B-granular:
// fragment reads (16 rows x 16B) spread over all 8 slots (2-way = free).
__device__ __forceinline__ int swz(int row, int kb) {
  return (row * 64 + kb) ^ ((row & 7) << 4);
}

// async global->LDS, 16B per lane; LDS dest must be wave-uniform base.
__device__ __forceinline__ void gload16(const void* g, void* l) {
  __builtin_amdgcn_global_load_lds(
      (const __attribute__((address_space(1))) unsigned int*)g,
      (__attribute__((address_space(3))) unsigned int*)l, 16, 0, 0);
}

// Inverse of swz at the linear byte x in [0,8192): which logical (row,kb)
// must sit at linear x so that reads via swz() find it.
__device__ __forceinline__ void inv_swz(int x, int& row, int& kb) {
  row = ((x >> 7) << 1) | (((x >> 6) & 1) ^ ((x >> 8) & 1));
  kb = (x & 63) ^ ((row & 3) << 4);
}

// ================= tcvt: dst[b][d][n] (f16) = src[b][n][d] (f32) =================
__global__ __launch_bounds__(256) void tcvt(const float* __restrict__ src,
                                            _Float16* __restrict__ dst) {
  const int b = blockIdx.z;
  const int d0 = blockIdx.x * 64, n0 = blockIdx.y * 64;
  src += (size_t)b * 512 * 512;
  dst += (size_t)b * 512 * 512;
  const int dl = threadIdx.x & 63, nch = (threadIdx.x >> 6) * 16;
  const float* ps = src + (size_t)(n0 + nch) * 512 + d0 + dl;
  h8 o[2];
#pragma unroll
  for (int e = 0; e < 16; ++e)
    o[e >> 3][e & 7] = (_Float16)ps[(size_t)e * 512];
  _Float16* pd = dst + (size_t)(d0 + dl) * 512 + n0 + nch;
  *reinterpret_cast<h8*>(pd) = o[0];
  *reinterpret_cast<h8*>(pd + 8) = o[1];
}

// ================= sim = pre @ hyp^T, 2-term f16 split (3 MFMAs) =================
__global__ __launch_bounds__(256, 2) void sim_mfma(const float* __restrict__ pre,
                                                   const float* __restrict__ hyp,
                                                   float* __restrict__ sim) {
  const int b = blockIdx.z;
  const int p0 = blockIdx.y * 128, h0 = blockIdx.x * 128;

  __shared__ __align__(16) char sAh[8192], sAl[8192], sBh[8192], sBl[8192];

  const int t = threadIdx.x;
  const int r = t >> 1, kh = t & 1;
  const int lane = t & 63, wid = t >> 6;
  const int l15 = lane & 15, l4 = lane >> 4;
  const int wr = (wid >> 1) * 64, wc = (wid & 1) * 64;

  f32x4 acc[4][4] = {};

  const float* pA = pre + (size_t)b * PP * DD + (size_t)(p0 + r) * DD + kh * 16;
  const float* pB = hyp + (size_t)b * HH * DD + (size_t)(h0 + r) * DD + kh * 16;

  for (int kk = 0; kk < DD; kk += 32) {
    f32x4 ra[4], rb[4];
#pragma unroll
    for (int c = 0; c < 4; ++c) {
      ra[c] = *reinterpret_cast<const f32x4*>(pA + kk + c * 4);
      rb[c] = *reinterpret_cast<const f32x4*>(pB + kk + c * 4);
    }
    __syncthreads();
    h8 vah[2], val[2], vbh[2], vbl[2];
#pragma unroll
    for (int c = 0; c < 4; ++c)
#pragma unroll
      for (int e = 0; e < 4; ++e) {
        const int idx = c * 4 + e;
        float fa = ra[c][e], fb = rb[c][e];
        _Float16 ha = (_Float16)fa, hb = (_Float16)fb;
        vah[idx >> 3][idx & 7] = ha;
        val[idx >> 3][idx & 7] = (_Float16)(fa - (float)ha);
        vbh[idx >> 3][idx & 7] = hb;
        vbl[idx >> 3][idx & 7] = (_Float16)(fb - (float)hb);
      }
    *reinterpret_cast<h8*>(sAh + swz(r, kh * 32)) = vah[0];
    *reinterpret_cast<h8*>(sAh + swz(r, kh * 32 + 16)) = vah[1];
    *reinterpret_cast<h8*>(sAl + swz(r, kh * 32)) = val[0];
    *reinterpret_cast<h8*>(sAl + swz(r, kh * 32 + 16)) = val[1];
    *reinterpret_cast<h8*>(sBh + swz(r, kh * 32)) = vbh[0];
    *reinterpret_cast<h8*>(sBh + swz(r, kh * 32 + 16)) = vbh[1];
    *reinterpret_cast<h8*>(sBl + swz(r, kh * 32)) = vbl[0];
    *reinterpret_cast<h8*>(sBl + swz(r, kh * 32 + 16)) = vbl[1];
    __syncthreads();

    h8 Ah[4], Al[4], Bh[4], Bl[4];
#pragma unroll
    for (int i = 0; i < 4; ++i) {
      Ah[i] = *reinterpret_cast<const h8*>(sAh + swz(wr + i * 16 + l15, l4 * 16));
      Al[i] = *reinterpret_cast<const h8*>(sAl + swz(wr + i * 16 + l15, l4 * 16));
      Bh[i] = *reinterpret_cast<const h8*>(sBh + swz(wc + i * 16 + l15, l4 * 16));
      Bl[i] = *reinterpret_cast<const h8*>(sBl + swz(wc + i * 16 + l15, l4 * 16));
    }
#pragma unroll
    for (int i = 0; i < 4; ++i)
#pragma unroll
      for (int j = 0; j < 4; ++j) {
        acc[i][j] = MFMA16(Ah[i], Bh[j], acc[i][j]);
        acc[i][j] = MFMA16(Ah[i], Bl[j], acc[i][j]);
        acc[i][j] = MFMA16(Al[i], Bh[j], acc[i][j]);
      }
  }

  float* S = sim + (size_t)b * PP * HH;
#pragma unroll
  for (int i = 0; i < 4; ++i)
#pragma unroll
    for (int j = 0; j < 4; ++j)
#pragma unroll
      for (int rr = 0; rr < 4; ++rr)
        S[(size_t)(p0 + wr + i * 16 + l4 * 4 + rr) * HH + h0 + wc + j * 16 + l15] =
            acc[i][j][rr];
}

// ================= stats over h (axis=2): one wave per row =================
__global__ __launch_bounds__(256) void stats_rows(const float* __restrict__ sim,
                                                  const int* __restrict__ pmask,
                                                  float* __restrict__ maxA,
                                                  float* __restrict__ sumA) {
  const int wid = threadIdx.x >> 6, lane = threadIdx.x & 63;
  const int row = blockIdx.x * 4 + wid;          // b*PP + p
  const float* s = sim + (size_t)row * HH + lane * 8;
  const float c = (pmask[row] == 0) ? NEG_MASK : 0.f;

  f32x4 v0 = *reinterpret_cast<const f32x4*>(s);
  f32x4 v1 = *reinterpret_cast<const f32x4*>(s + 4);
  float tv[8] = {v0[0] + c, v0[1] + c, v0[2] + c, v0[3] + c,
                 v1[0] + c, v1[1] + c, v1[2] + c, v1[3] + c};
  float m = tv[0];
#pragma unroll
  for (int e = 1; e < 8; ++e) m = fmaxf(m, tv[e]);
#pragma unroll
  for (int o = 1; o < 64; o <<= 1) m = fmaxf(m, __shfl_xor(m, o, 64));
  float sum = 0.f;
#pragma unroll
  for (int e = 0; e < 8; ++e) sum += __expf(tv[e] - m);
#pragma unroll
  for (int o = 1; o < 64; o <<= 1) sum += __shfl_xor(sum, o, 64);
  if (lane == 0) { maxA[row] = m; sumA[row] = sum; }
}

// ================= stats over p (axis=1): 64 h per block, 4 p-segments =================
__global__ __launch_bounds__(256) void stats_cols(const float* __restrict__ sim,
                                                  const int* __restrict__ hmask,
                                                  float* __restrict__ maxB,
                                                  float* __restrict__ sumB) {
  const int b = blockIdx.y;
  const int th = threadIdx.x & 63, seg = threadIdx.x >> 6;
  const int h = blockIdx.x * 64 + th;
  const float* s = sim + (size_t)b * PP * HH + h;
  const float c = (hmask[b * HH + h] == 0) ? NEG_MASK : 0.f;

  __shared__ float red[4][64];

  float m = -3.4e38f;
  for (int p = seg * 128; p < seg * 128 + 128; ++p)
    m = fmaxf(m, s[(size_t)p * HH] + c);
  red[seg][th] = m;
  __syncthreads();
  m = fmaxf(fmaxf(red[0][th], red[1][th]), fmaxf(red[2][th], red[3][th]));

  float sum = 0.f;
  for (int p = seg * 128; p < seg * 128 + 128; ++p)
    sum += __expf((s[(size_t)p * HH] + c) - m);
  __syncthreads();
  red[seg][th] = sum;
  __syncthreads();
  if (seg == 0) {
    maxB[b * HH + h] = m;
    sumB[b * HH + h] = red[0][th] + red[1][th] + red[2][th] + red[3][th];
  }
}

// ================= att_a: softmax_h(sim) @ hyp  (V from hypT via gload_lds) =================
__global__ __launch_bounds__(256, 3) void att_a_mfma(const float* __restrict__ sim,
                                                     const _Float16* __restrict__ hypT,
                                                     const int* __restrict__ pmask,
                                                     const float* __restrict__ maxA,
                                                     const float* __restrict__ sumA,
                                                     float* __restrict__ out) {
  const int b = blockIdx.z;
  const int p0 = blockIdx.y * 128, d0 = blockIdx.x * 128;
  const float* S = sim + (size_t)b * PP * HH;
  const _Float16* T = hypT + (size_t)b * DD * HH;

  __shared__ __align__(16) char sW[8192], sV[8192];

  const int t = threadIdx.x;
  const int lane = t & 63, wid = t >> 6;
  const int l15 = lane & 15, l4 = lane >> 4;
  const int wr = (wid >> 1) * 64, wc = (wid & 1) * 64;

  const int r = t >> 1, kh = t & 1;
  const float cA = (pmask[b * PP + p0 + r] == 0) ? NEG_MASK : 0.f;
  const float mA = maxA[b * PP + p0 + r];

  // pre-swizzled global sources for the two 4KB gload halves
  int row0, kb0, row1, kb1;
  inv_swz(t * 16, row0, kb0);
  inv_swz(4096 + t * 16, row1, kb1);
  const _Float16* srcV0 = T + (size_t)(d0 + row0) * HH + (kb0 >> 1);
  const _Float16* srcV1 = T + (size_t)(d0 + row1) * HH + (kb1 >> 1);
  void* lb0 = sV + wid * 1024;
  void* lb1 = sV + 4096 + wid * 1024;

  const float* pS = S + (size_t)(p0 + r) * HH + kh * 16;
  f32x4 rs[4];
#pragma unroll
  for (int c = 0; c < 4; ++c) rs[c] = *reinterpret_cast<const f32x4*>(pS + c * 4);

  f32x4 acc[4][4] = {};

  for (int kk = 0; kk < HH; kk += 32) {
    h8 wv[2];
#pragma unroll
    for (int c = 0; c < 4; ++c)
#pragma unroll
      for (int e = 0; e < 4; ++e) {
        const int idx = c * 4 + e;
        wv[idx >> 3][idx & 7] = (_Float16)__expf((rs[c][e] + cA) - mA);
      }
    __syncthreads();
    gload16(srcV0 + kk, lb0);
    gload16(srcV1 + kk, lb1);
    *reinterpret_cast<h8*>(sW + swz(r, kh * 32)) = wv[0];
    *reinterpret_cast<h8*>(sW + swz(r, kh * 32 + 16)) = wv[1];
    __syncthreads();
    if (kk + 32 < HH) {
#pragma unroll
      for (int c = 0; c < 4; ++c)
        rs[c] = *reinterpret_cast<const f32x4*>(pS + kk + 32 + c * 4);
    }
    h8 Wf[4], Vf[4];
#pragma unroll
    for (int i = 0; i < 4; ++i) {
      Wf[i] = *reinterpret_cast<const h8*>(sW + swz(wr + i * 16 + l15, l4 * 16));
      Vf[i] = *reinterpret_cast<const h8*>(sV + swz(wc + i * 16 + l15, l4 * 16));
    }
#pragma unroll
    for (int i = 0; i < 4; ++i)
#pragma unroll
      for (int j = 0; j < 4; ++j)
        acc[i][j] = MFMA16(Wf[i], Vf[j], acc[i][j]);
  }

  float* O = out + (size_t)b * PP * DD;
#pragma unroll
  for (int i = 0; i < 4; ++i)
#pragma unroll
    for (int rr = 0; rr < 4; ++rr) {
      const int prow = p0 + wr + i * 16 + l4 * 4 + rr;
      const float inv = 1.f / sumA[b * PP + prow];
#pragma unroll
      for (int j = 0; j < 4; ++j)
        O[(size_t)prow * DD + d0 + wc + j * 16 + l15] = acc[i][j][rr] * inv;
    }
}

// ================= att_b: softmax_p(sim)^T @ pre  (U from preT via gload_lds) =================
__global__ __launch_bounds__(256, 3) void att_b_mfma(const float* __restrict__ sim,
                                                     const _Float16* __restrict__ preT,
                                                     const int* __restrict__ hmask,
                                                     const float* __restrict__ maxB,
                                                     const float* __restrict__ sumB,
                                                     float* __restrict__ out) {
  const int b = blockIdx.z;
  const int h0 = blockIdx.y * 128, d0 = blockIdx.x * 128;
  const float* S = sim + (size_t)b * PP * HH;
  const _Float16* T = preT + (size_t)b * DD * PP;

  __shared__ __align__(16) char sW[8192], sU[8192];

  const int t = threadIdx.x;
  const int lane = t & 63, wid = t >> 6;
  const int l15 = lane & 15, l4 = lane >> 4;
  const int wr = (wid >> 1) * 64, wc = (wid & 1) * 64;

  const int hp = t >> 2, kq = t & 3;      // W^T staging: 2 h-rows, 8 k each
  float cH[2], mB[2];
#pragma unroll
  for (int hh = 0; hh < 2; ++hh) {
    const int h = h0 + hp * 2 + hh;
    cH[hh] = (hmask[b * HH + h] == 0) ? NEG_MASK : 0.f;
    mB[hh] = maxB[b * HH + h];
  }

  int row0, kb0, row1, kb1;
  inv_swz(t * 16, row0, kb0);
  inv_swz(4096 + t * 16, row1, kb1);
  const _Float16* srcU0 = T + (size_t)(d0 + row0) * PP + (kb0 >> 1);
  const _Float16* srcU1 = T + (size_t)(d0 + row1) * PP + (kb1 >> 1);
  void* lb0 = sU + wid * 1024;
  void* lb1 = sU + 4096 + wid * 1024;

  const float* pS0 = S + h0 + hp * 2;
  f32x2 rw[8];
#pragma unroll
  for (int jj = 0; jj < 8; ++jj)
    rw[jj] = *reinterpret_cast<const f32x2*>(pS0 + (size_t)(kq * 8 + jj) * HH);

  f32x4 acc[4][4] = {};

  for (int kk = 0; kk < PP; kk += 32) {
    h8 w0, w1;
#pragma unroll
    for (int jj = 0; jj < 8; ++jj) {
      w0[jj] = (_Float16)__expf((rw[jj][0] + cH[0]) - mB[0]);
      w1[jj] = (_Float16)__expf((rw[jj][1] + cH[1]) - mB[1]);
    }
    __syncthreads();
    gload16(srcU0 + kk, lb0);
    gload16(srcU1 + kk, lb1);
    *reinterpret_cast<h8*>(sW + swz(hp * 2 + 0, kq * 16)) = w0;
    *reinterpret_cast<h8*>(sW + swz(hp * 2 + 1, kq * 16)) = w1;
    __syncthreads();
    if (kk + 32 < PP) {
#pragma unroll
      for (int jj = 0; jj < 8; ++jj)
        rw[jj] = *reinterpret_cast<const f32x2*>(pS0 + (size_t)(kk + 32 + kq * 8 + jj) * HH);
    }
    h8 Wf[4], Uf[4];
#pragma unroll
    for (int i = 0; i < 4; ++i) {
      Wf[i] = *reinterpret_cast<const h8*>(sW + swz(wr + i * 16 + l15, l4 * 16));
      Uf[i] = *reinterpret_cast<const h8*>(sU + swz(wc + i * 16 + l15, l4 * 16));
    }
#pragma unroll
    for (int i = 0; i < 4; ++i)
#pragma unroll
      for (int j = 0; j < 4; ++j)
        acc[i][j] = MFMA16(Wf[i], Uf[j], acc[i][j]);
  }

  float* O = out + (size_t)b * HH * DD;
#pragma unroll
  for (int i = 0; i < 4; ++i)
#pragma unroll
    for (int rr = 0; rr < 4; ++rr) {
      const int hrow = h0 + wr + i * 16 + l4 * 4 + rr;
      const float inv = 1.f / sumB[b * HH + hrow];
#pragma unroll
      for (int j = 0; j < 4; ++j)
        O[(size_t)hrow * DD + d0 + wc + j * 16 + l15] = acc[i][j][rr] * inv;
    }
}

extern "C" void kernel_launch(void* const* d_in, const int* in_sizes, int n_in,
                              void* d_out, int out_size, void* d_ws, size_t ws_size,
                              hipStream_t stream) {
  const float* pre  = (const float*)d_in[0];
  const int* pmask  = (const int*)d_in[1];
  const float* hyp  = (const float*)d_in[2];
  const int* hmask  = (const int*)d_in[3];

  float* out0 = (float*)d_out;                    // attended_premises   [B,P,D]
  float* out1 = out0 + (size_t)BB * PP * DD;      // attended_hypothesis [B,H,D]

  float* sim = (float*)d_ws;                      // [B,P,H] f32, 64MB
  _Float16* hypT = (_Float16*)(sim + (size_t)BB * PP * HH);   // [B,D,H] f16, 32MB
  _Float16* preT = hypT + (size_t)BB * DD * HH;               // [B,D,P] f16, 32MB
  float* maxA = (float*)(preT + (size_t)BB * DD * PP);        // [B,P]
  float* sumA = maxA + BB * PP;
  float* maxB = sumA + BB * PP;                               // [B,H]
  float* sumB = maxB + BB * HH;

  tcvt<<<dim3(8, 8, BB), 256, 0, stream>>>(hyp, hypT);
  tcvt<<<dim3(8, 8, BB), 256, 0, stream>>>(pre, preT);
  sim_mfma<<<dim3(HH / 128, PP / 128, BB), 256, 0, stream>>>(pre, hyp, sim);
  stats_rows<<<dim3(BB * PP / 4), 256, 0, stream>>>(sim, pmask, maxA, sumA);
  stats_cols<<<dim3(HH / 64, BB), 256, 0, stream>>>(sim, hmask, maxB, sumB);
  att_a_mfma<<<dim3(DD / 128, PP / 128, BB), 256, 0, stream>>>(sim, hypT, pmask, maxA, sumA, out0);
  att_b_mfma<<<dim3(DD / 128, HH / 128, BB), 256, 0, stream>>>(sim, preT, hmask, maxB, sumB, out1);
}

// Round 4
// 487.840 us; speedup vs baseline: 1.0143x; 1.0143x over previous
//
#include <hip/hip_runtime.h>
#include <hip/hip_bf16.h>
#include <math.h>

#define NEG_MASK -999999.0f

constexpr int BB = 64, PP = 512, HH = 512, DD = 512;

typedef _Float16 h8    __attribute__((ext_vector_type(8)));   // MFMA A/B operand (4 VGPRs)
typedef float    f32x4 __attribute__((ext_vector_type(4)));
typedef float    f32x2 __attribute__((ext_vector_type(2)));

#define MFMA16(a, b, c) __builtin_amdgcn_mfma_f32_16x16x32_f16(a, b, c, 0, 0, 0)

// Bijective XOR swizzle for [128 rows][64 bytes] LDS tiles, 16B-granular.
__device__ __forceinline__ int swz(int row, int kb) {
  return (row * 64 + kb) ^ ((row & 7) << 4);
}

// async global->LDS, 16B per lane; LDS dest is wave-uniform base + lane*16.
__device__ __forceinline__ void gload16(const void* g, void* l) {
  __builtin_amdgcn_global_load_lds(
      (const __attribute__((address_space(1))) unsigned int*)g,
      (__attribute__((address_space(3))) unsigned int*)l, 16, 0, 0);
}

// Inverse of swz at linear byte x: which logical (row,kb) sits at x.
__device__ __forceinline__ void inv_swz(int x, int& row, int& kb) {
  row = ((x >> 7) << 1) | (((x >> 6) & 1) ^ ((x >> 8) & 1));
  kb = (x & 63) ^ ((row & 3) << 4);
}

// XCD swizzle for 4x4x64 = 1024-block grids: each XCD gets 8 whole batches.
__device__ __forceinline__ void xcd_remap(int& bx, int& by, int& bz) {
  int flat = blockIdx.x + 4 * blockIdx.y + 16 * blockIdx.z;   // [0,1024)
  int nid = (flat & 7) * 128 + (flat >> 3);
  bx = nid & 3; by = (nid >> 2) & 3; bz = nid >> 4;
}

// ================= tcvt: dst[b][d][n] (f16) = src[b][n][d] (f32) =================
__global__ __launch_bounds__(256) void tcvt(const float* __restrict__ src,
                                            _Float16* __restrict__ dst) {
  const int b = blockIdx.z;
  const int d0 = blockIdx.x * 64, n0 = blockIdx.y * 64;
  src += (size_t)b * 512 * 512;
  dst += (size_t)b * 512 * 512;
  const int dl = threadIdx.x & 63, nch = (threadIdx.x >> 6) * 16;
  const float* ps = src + (size_t)(n0 + nch) * 512 + d0 + dl;
  h8 o[2];
#pragma unroll
  for (int e = 0; e < 16; ++e)
    o[e >> 3][e & 7] = (_Float16)ps[(size_t)e * 512];
  _Float16* pd = dst + (size_t)(d0 + dl) * 512 + n0 + nch;
  *reinterpret_cast<h8*>(pd) = o[0];
  *reinterpret_cast<h8*>(pd + 8) = o[1];
}

// ================= tps: simT[b][h][p] = sim[b][p][h]  (f32, 64x64 LDS tiles) =================
__global__ __launch_bounds__(256) void tps(const float* __restrict__ sim,
                                           float* __restrict__ simT) {
  const int b = blockIdx.z;
  const int h0 = blockIdx.x * 64, p0 = blockIdx.y * 64;
  const float* S = sim + (size_t)b * PP * HH;
  float* T = simT + (size_t)b * HH * PP;

  __shared__ float L[64 * 67];   // L[p*67 + h], stride 67 breaks bank alignment

  const int tx = threadIdx.x & 15, ty = threadIdx.x >> 4;
#pragma unroll
  for (int pass = 0; pass < 4; ++pass) {
    const int p = ty + pass * 16;
    f32x4 v = *reinterpret_cast<const f32x4*>(S + (size_t)(p0 + p) * HH + h0 + tx * 4);
#pragma unroll
    for (int e = 0; e < 4; ++e) L[p * 67 + tx * 4 + e] = v[e];
  }
  __syncthreads();
#pragma unroll
  for (int pass = 0; pass < 4; ++pass) {
    const int h = ty + pass * 16;
    f32x4 w;
#pragma unroll
    for (int e = 0; e < 4; ++e) w[e] = L[(tx * 4 + e) * 67 + h];
    *reinterpret_cast<f32x4*>(T + (size_t)(h0 + h) * PP + p0 + tx * 4) = w;
  }
}

// ================= sim = pre @ hyp^T, 2-term f16 split (3 MFMAs) =================
__global__ __launch_bounds__(256, 4) void sim_mfma(const float* __restrict__ pre,
                                                   const float* __restrict__ hyp,
                                                   float* __restrict__ sim) {
  int bx, by, b;
  xcd_remap(bx, by, b);
  const int p0 = by * 128, h0 = bx * 128;

  __shared__ __align__(16) char sAh[8192], sAl[8192], sBh[8192], sBl[8192];

  const int t = threadIdx.x;
  const int r = t >> 1, kh = t & 1;
  const int lane = t & 63, wid = t >> 6;
  const int l15 = lane & 15, l4 = lane >> 4;
  const int wr = (wid >> 1) * 64, wc = (wid & 1) * 64;

  f32x4 acc[4][4] = {};

  const float* pA = pre + (size_t)b * PP * DD + (size_t)(p0 + r) * DD + kh * 16;
  const float* pB = hyp + (size_t)b * HH * DD + (size_t)(h0 + r) * DD + kh * 16;

  for (int kk = 0; kk < DD; kk += 32) {
    f32x4 ra[4], rb[4];
#pragma unroll
    for (int c = 0; c < 4; ++c) {
      ra[c] = *reinterpret_cast<const f32x4*>(pA + kk + c * 4);
      rb[c] = *reinterpret_cast<const f32x4*>(pB + kk + c * 4);
    }
    __syncthreads();
    h8 vah[2], val[2], vbh[2], vbl[2];
#pragma unroll
    for (int c = 0; c < 4; ++c)
#pragma unroll
      for (int e = 0; e < 4; ++e) {
        const int idx = c * 4 + e;
        float fa = ra[c][e], fb = rb[c][e];
        _Float16 ha = (_Float16)fa, hb = (_Float16)fb;
        vah[idx >> 3][idx & 7] = ha;
        val[idx >> 3][idx & 7] = (_Float16)(fa - (float)ha);
        vbh[idx >> 3][idx & 7] = hb;
        vbl[idx >> 3][idx & 7] = (_Float16)(fb - (float)hb);
      }
    *reinterpret_cast<h8*>(sAh + swz(r, kh * 32)) = vah[0];
    *reinterpret_cast<h8*>(sAh + swz(r, kh * 32 + 16)) = vah[1];
    *reinterpret_cast<h8*>(sAl + swz(r, kh * 32)) = val[0];
    *reinterpret_cast<h8*>(sAl + swz(r, kh * 32 + 16)) = val[1];
    *reinterpret_cast<h8*>(sBh + swz(r, kh * 32)) = vbh[0];
    *reinterpret_cast<h8*>(sBh + swz(r, kh * 32 + 16)) = vbh[1];
    *reinterpret_cast<h8*>(sBl + swz(r, kh * 32)) = vbl[0];
    *reinterpret_cast<h8*>(sBl + swz(r, kh * 32 + 16)) = vbl[1];
    __syncthreads();

    h8 Ah[4], Al[4], Bh[4], Bl[4];
#pragma unroll
    for (int i = 0; i < 4; ++i) {
      Ah[i] = *reinterpret_cast<const h8*>(sAh + swz(wr + i * 16 + l15, l4 * 16));
      Al[i] = *reinterpret_cast<const h8*>(sAl + swz(wr + i * 16 + l15, l4 * 16));
      Bh[i] = *reinterpret_cast<const h8*>(sBh + swz(wc + i * 16 + l15, l4 * 16));
      Bl[i] = *reinterpret_cast<const h8*>(sBl + swz(wc + i * 16 + l15, l4 * 16));
    }
#pragma unroll
    for (int i = 0; i < 4; ++i)
#pragma unroll
      for (int j = 0; j < 4; ++j) {
        acc[i][j] = MFMA16(Ah[i], Bh[j], acc[i][j]);
        acc[i][j] = MFMA16(Ah[i], Bl[j], acc[i][j]);
        acc[i][j] = MFMA16(Al[i], Bh[j], acc[i][j]);
      }
  }

  float* S = sim + (size_t)b * PP * HH;
#pragma unroll
  for (int i = 0; i < 4; ++i)
#pragma unroll
    for (int j = 0; j < 4; ++j)
#pragma unroll
      for (int rr = 0; rr < 4; ++rr)
        S[(size_t)(p0 + wr + i * 16 + l4 * 4 + rr) * HH + h0 + wc + j * 16 + l15] =
            acc[i][j][rr];
}

// ================= row stats: max/sum over last dim, one wave per row =================
__global__ __launch_bounds__(256) void stats_rows(const float* __restrict__ S,
                                                  const int* __restrict__ mask,
                                                  float* __restrict__ maxO,
                                                  float* __restrict__ sumO) {
  const int wid = threadIdx.x >> 6, lane = threadIdx.x & 63;
  const int row = blockIdx.x * 4 + wid;
  const float* s = S + (size_t)row * 512 + lane * 8;
  const float c = (mask[row] == 0) ? NEG_MASK : 0.f;

  f32x4 v0 = *reinterpret_cast<const f32x4*>(s);
  f32x4 v1 = *reinterpret_cast<const f32x4*>(s + 4);
  float tv[8] = {v0[0] + c, v0[1] + c, v0[2] + c, v0[3] + c,
                 v1[0] + c, v1[1] + c, v1[2] + c, v1[3] + c};
  float m = tv[0];
#pragma unroll
  for (int e = 1; e < 8; ++e) m = fmaxf(m, tv[e]);
#pragma unroll
  for (int o = 1; o < 64; o <<= 1) m = fmaxf(m, __shfl_xor(m, o, 64));
  float sum = 0.f;
#pragma unroll
  for (int e = 0; e < 8; ++e) sum += __expf(tv[e] - m);
#pragma unroll
  for (int o = 1; o < 64; o <<= 1) sum += __shfl_xor(sum, o, 64);
  if (lane == 0) { maxO[row] = m; sumO[row] = sum; }
}

// ================= stats over p (axis=1), column walk — fallback only =================
__global__ __launch_bounds__(256) void stats_cols(const float* __restrict__ sim,
                                                  const int* __restrict__ hmask,
                                                  float* __restrict__ maxB,
                                                  float* __restrict__ sumB) {
  const int b = blockIdx.y;
  const int th = threadIdx.x & 63, seg = threadIdx.x >> 6;
  const int h = blockIdx.x * 64 + th;
  const float* s = sim + (size_t)b * PP * HH + h;
  const float c = (hmask[b * HH + h] == 0) ? NEG_MASK : 0.f;

  __shared__ float red[4][64];

  float m = -3.4e38f;
  for (int p = seg * 128; p < seg * 128 + 128; ++p)
    m = fmaxf(m, s[(size_t)p * HH] + c);
  red[seg][th] = m;
  __syncthreads();
  m = fmaxf(fmaxf(red[0][th], red[1][th]), fmaxf(red[2][th], red[3][th]));

  float sum = 0.f;
  for (int p = seg * 128; p < seg * 128 + 128; ++p)
    sum += __expf((s[(size_t)p * HH] + c) - m);
  __syncthreads();
  red[seg][th] = sum;
  __syncthreads();
  if (seg == 0) {
    maxB[b * HH + h] = m;
    sumB[b * HH + h] = red[0][th] + red[1][th] + red[2][th] + red[3][th];
  }
}

// ================= unified att: out[b][n][d] = softmax_k(S[b][n][k]) @ T[b][d][k]^T ============
__global__ __launch_bounds__(256, 4) void att(const float* __restrict__ S_,
                                              const _Float16* __restrict__ T_,
                                              const int* __restrict__ mask,
                                              const float* __restrict__ maxI,
                                              const float* __restrict__ sumI,
                                              float* __restrict__ out) {
  int bx, by, b;
  xcd_remap(bx, by, b);
  const int n0 = by * 128, d0 = bx * 128;
  const float* S = S_ + (size_t)b * 512 * 512;
  const _Float16* T = T_ + (size_t)b * 512 * 512;

  __shared__ __align__(16) char sW[8192], sV[8192];

  const int t = threadIdx.x;
  const int lane = t & 63, wid = t >> 6;
  const int l15 = lane & 15, l4 = lane >> 4;
  const int wr = (wid >> 1) * 64, wc = (wid & 1) * 64;

  const int r = t >> 1, kh = t & 1;
  const float cA = (mask[b * 512 + n0 + r] == 0) ? NEG_MASK : 0.f;
  const float mA = maxI[b * 512 + n0 + r];

  int row0, kb0, row1, kb1;
  inv_swz(t * 16, row0, kb0);
  inv_swz(4096 + t * 16, row1, kb1);
  const _Float16* srcV0 = T + (size_t)(d0 + row0) * 512 + (kb0 >> 1);
  const _Float16* srcV1 = T + (size_t)(d0 + row1) * 512 + (kb1 >> 1);
  void* lb0 = sV + wid * 1024;
  void* lb1 = sV + 4096 + wid * 1024;

  const float* pS = S + (size_t)(n0 + r) * 512 + kh * 16;
  f32x4 rs[4];
#pragma unroll
  for (int c = 0; c < 4; ++c) rs[c] = *reinterpret_cast<const f32x4*>(pS + c * 4);

  f32x4 acc[4][4] = {};

  for (int kk = 0; kk < 512; kk += 32) {
    h8 wv[2];
#pragma unroll
    for (int c = 0; c < 4; ++c)
#pragma unroll
      for (int e = 0; e < 4; ++e) {
        const int idx = c * 4 + e;
        wv[idx >> 3][idx & 7] = (_Float16)__expf((rs[c][e] + cA) - mA);
      }
    __syncthreads();
    gload16(srcV0 + kk, lb0);
    gload16(srcV1 + kk, lb1);
    *reinterpret_cast<h8*>(sW + swz(r, kh * 32)) = wv[0];
    *reinterpret_cast<h8*>(sW + swz(r, kh * 32 + 16)) = wv[1];
    __syncthreads();
    if (kk + 32 < 512) {
#pragma unroll
      for (int c = 0; c < 4; ++c)
        rs[c] = *reinterpret_cast<const f32x4*>(pS + kk + 32 + c * 4);
    }
    h8 Wf[4], Vf[4];
#pragma unroll
    for (int i = 0; i < 4; ++i) {
      Wf[i] = *reinterpret_cast<const h8*>(sW + swz(wr + i * 16 + l15, l4 * 16));
      Vf[i] = *reinterpret_cast<const h8*>(sV + swz(wc + i * 16 + l15, l4 * 16));
    }
#pragma unroll
    for (int i = 0; i < 4; ++i)
#pragma unroll
      for (int j = 0; j < 4; ++j)
        acc[i][j] = MFMA16(Wf[i], Vf[j], acc[i][j]);
  }

  float* O = out + (size_t)b * 512 * 512;
#pragma unroll
  for (int i = 0; i < 4; ++i)
#pragma unroll
    for (int rr = 0; rr < 4; ++rr) {
      const int nrow = n0 + wr + i * 16 + l4 * 4 + rr;
      const float inv = 1.f / sumI[b * 512 + nrow];
#pragma unroll
      for (int j = 0; j < 4; ++j)
        O[(size_t)nrow * 512 + d0 + wc + j * 16 + l15] = acc[i][j][rr] * inv;
    }
}

// ================= fallback att_b (round-3, column-strided W) =================
__global__ __launch_bounds__(256, 3) void att_b_slow(const float* __restrict__ sim,
                                                     const _Float16* __restrict__ preT,
                                                     const int* __restrict__ hmask,
                                                     const float* __restrict__ maxB,
                                                     const float* __restrict__ sumB,
                                                     float* __restrict__ out) {
  const int b = blockIdx.z;
  const int h0 = blockIdx.y * 128, d0 = blockIdx.x * 128;
  const float* S = sim + (size_t)b * PP * HH;
  const _Float16* T = preT + (size_t)b * DD * PP;

  __shared__ __align__(16) char sW[8192], sU[8192];

  const int t = threadIdx.x;
  const int lane = t & 63, wid = t >> 6;
  const int l15 = lane & 15, l4 = lane >> 4;
  const int wr = (wid >> 1) * 64, wc = (wid & 1) * 64;

  const int hp = t >> 2, kq = t & 3;
  float cH[2], mB[2];
#pragma unroll
  for (int hh = 0; hh < 2; ++hh) {
    const int h = h0 + hp * 2 + hh;
    cH[hh] = (hmask[b * HH + h] == 0) ? NEG_MASK : 0.f;
    mB[hh] = maxB[b * HH + h];
  }

  int row0, kb0, row1, kb1;
  inv_swz(t * 16, row0, kb0);
  inv_swz(4096 + t * 16, row1, kb1);
  const _Float16* srcU0 = T + (size_t)(d0 + row0) * PP + (kb0 >> 1);
  const _Float16* srcU1 = T + (size_t)(d0 + row1) * PP + (kb1 >> 1);
  void* lb0 = sU + wid * 1024;
  void* lb1 = sU + 4096 + wid * 1024;

  const float* pS0 = S + h0 + hp * 2;
  f32x2 rw[8];
#pragma unroll
  for (int jj = 0; jj < 8; ++jj)
    rw[jj] = *reinterpret_cast<const f32x2*>(pS0 + (size_t)(kq * 8 + jj) * HH);

  f32x4 acc[4][4] = {};

  for (int kk = 0; kk < PP; kk += 32) {
    h8 w0, w1;
#pragma unroll
    for (int jj = 0; jj < 8; ++jj) {
      w0[jj] = (_Float16)__expf((rw[jj][0] + cH[0]) - mB[0]);
      w1[jj] = (_Float16)__expf((rw[jj][1] + cH[1]) - mB[1]);
    }
    __syncthreads();
    gload16(srcU0 + kk, lb0);
    gload16(srcU1 + kk, lb1);
    *reinterpret_cast<h8*>(sW + swz(hp * 2 + 0, kq * 16)) = w0;
    *reinterpret_cast<h8*>(sW + swz(hp * 2 + 1, kq * 16)) = w1;
    __syncthreads();
    if (kk + 32 < PP) {
#pragma unroll
      for (int jj = 0; jj < 8; ++jj)
        rw[jj] = *reinterpret_cast<const f32x2*>(pS0 + (size_t)(kk + 32 + kq * 8 + jj) * HH);
    }
    h8 Wf[4], Uf[4];
#pragma unroll
    for (int i = 0; i < 4; ++i) {
      Wf[i] = *reinterpret_cast<const h8*>(sW + swz(wr + i * 16 + l15, l4 * 16));
      Uf[i] = *reinterpret_cast<const h8*>(sU + swz(wc + i * 16 + l15, l4 * 16));
    }
#pragma unroll
    for (int i = 0; i < 4; ++i)
#pragma unroll
      for (int j = 0; j < 4; ++j)
        acc[i][j] = MFMA16(Wf[i], Uf[j], acc[i][j]);
  }

  float* O = out + (size_t)b * HH * DD;
#pragma unroll
  for (int i = 0; i < 4; ++i)
#pragma unroll
    for (int rr = 0; rr < 4; ++rr) {
      const int hrow = h0 + wr + i * 16 + l4 * 4 + rr;
      const float inv = 1.f / sumB[b * HH + hrow];
#pragma unroll
      for (int j = 0; j < 4; ++j)
        O[(size_t)hrow * DD + d0 + wc + j * 16 + l15] = acc[i][j][rr] * inv;
    }
}

extern "C" void kernel_launch(void* const* d_in, const int* in_sizes, int n_in,
                              void* d_out, int out_size, void* d_ws, size_t ws_size,
                              hipStream_t stream) {
  const float* pre  = (const float*)d_in[0];
  const int* pmask  = (const int*)d_in[1];
  const float* hyp  = (const float*)d_in[2];
  const int* hmask  = (const int*)d_in[3];

  float* out0 = (float*)d_out;                    // attended_premises   [B,P,D]
  float* out1 = out0 + (size_t)BB * PP * DD;      // attended_hypothesis [B,H,D]

  char* ws = (char*)d_ws;
  float* sim = (float*)ws;                                   // 64MB
  _Float16* hypT = (_Float16*)(ws + 67108864ULL);            // 32MB [B,D,H]
  _Float16* preT = (_Float16*)(ws + 100663296ULL);           // 32MB [B,D,P]
  float* maxA = (float*)(ws + 134217728ULL);                 // [B,P]
  float* sumA = maxA + BB * PP;
  float* maxB = sumA + BB * PP;                              // [B,H]
  float* sumB = maxB + BB * HH;
  float* simT = (float*)(ws + 134742016ULL);                 // 64MB [B,H,P]
  const bool big = ws_size >= 134742016ULL + 67108864ULL;

  tcvt<<<dim3(8, 8, BB), 256, 0, stream>>>(hyp, hypT);
  tcvt<<<dim3(8, 8, BB), 256, 0, stream>>>(pre, preT);
  sim_mfma<<<dim3(4, 4, BB), 256, 0, stream>>>(pre, hyp, sim);
  stats_rows<<<dim3(BB * PP / 4), 256, 0, stream>>>(sim, pmask, maxA, sumA);

  if (big) {
    tps<<<dim3(8, 8, BB), 256, 0, stream>>>(sim, simT);
    stats_rows<<<dim3(BB * HH / 4), 256, 0, stream>>>(simT, hmask, maxB, sumB);
    att<<<dim3(4, 4, BB), 256, 0, stream>>>(sim, hypT, pmask, maxA, sumA, out0);
    att<<<dim3(4, 4, BB), 256, 0, stream>>>(simT, preT, hmask, maxB, sumB, out1);
  } else {
    stats_cols<<<dim3(HH / 64, BB), 256, 0, stream>>>(sim, hmask, maxB, sumB);
    att<<<dim3(4, 4, BB), 256, 0, stream>>>(sim, hypT, pmask, maxA, sumA, out0);
    att_b_slow<<<dim3(4, 4, BB), 256, 0, stream>>>(sim, preT, hmask, maxB, sumB, out1);
  }
}